// Round 5
// baseline (132.006 us; speedup 1.0000x reference)
//
#include <hip/hip_runtime.h>
#include <math.h>

// VQ-VAE vector quantizer for MI355X (gfx950).
// z: [32768, 64] fp32, codebook: [1024, 64] fp32.
// Outputs (flat float32, concatenated): quantized_st [32768*64], vq_loss [1],
// indices [32768] (as float), perplexity [1].
//
// R5: R4 was latency-bound (MfmaUtil 11.6%, VALUBusy 15.6%, Occupancy 17.7%):
// 512 blocks x 4 waves = 2 waves/SIMD, nothing hides the per-kt B-load +
// MFMA-chain latency. Fix: 32 rows/block (mt=2) -> 1024 blocks = 4 waves/SIMD
// (launch_bounds(256,4), VGPR cap 128; LDS ~28.5 KB -> 4 blocks/CU fits).
// Numerics unchanged from R4 (3-term split-bf16 + exact fp32 recheck when
// top-2 margin < 1e-3).

#define D 64
#define KC 1024
#define MT 2              // 16-row m-tiles per wave
#define ROWS (MT * 16)    // 32 rows per block

typedef short short8 __attribute__((ext_vector_type(8)));
typedef short short4v __attribute__((ext_vector_type(4)));
typedef float f32x4 __attribute__((ext_vector_type(4)));

__device__ __forceinline__ unsigned short f2bf(float x) {
  unsigned int u = __float_as_uint(x);
  unsigned int r = (u + 0x7fffu + ((u >> 16) & 1u)) >> 16;
  return (unsigned short)r;
}
__device__ __forceinline__ float bf2f(unsigned short h) {
  return __uint_as_float((unsigned int)h << 16);
}

// Precompute: exact fp32 code norms, split-bf16 codebook
// bsplit[k][128] = [e_hi(64) | e_lo(64)], zero hist/loss.
__global__ __launch_bounds__(256) void vq_prep(
    const float* __restrict__ cb, unsigned short* __restrict__ bsplit,
    float* __restrict__ cbn, unsigned int* __restrict__ hist,
    float* __restrict__ loss_acc) {
  const int k = blockIdx.x * 256 + threadIdx.x;  // 0..1023
  const float4* e = (const float4*)(cb + (size_t)k * D);
  unsigned short* bp = bsplit + (size_t)k * 128;
  float s0 = 0.f, s1 = 0.f, s2 = 0.f, s3 = 0.f;
#pragma unroll
  for (int i = 0; i < 16; ++i) {
    float4 v = e[i];
    s0 = fmaf(v.x, v.x, s0);
    s1 = fmaf(v.y, v.y, s1);
    s2 = fmaf(v.z, v.z, s2);
    s3 = fmaf(v.w, v.w, s3);
    unsigned short h0 = f2bf(v.x), h1 = f2bf(v.y), h2 = f2bf(v.z), h3 = f2bf(v.w);
    short4v hv = {(short)h0, (short)h1, (short)h2, (short)h3};
    short4v lv = {(short)f2bf(v.x - bf2f(h0)), (short)f2bf(v.y - bf2f(h1)),
                  (short)f2bf(v.z - bf2f(h2)), (short)f2bf(v.w - bf2f(h3))};
    *(short4v*)(bp + i * 4) = hv;
    *(short4v*)(bp + 64 + i * 4) = lv;
  }
  cbn[k] = (s0 + s1) + (s2 + s3);
  hist[k] = 0u;
  if (k == 0) loss_acc[0] = 0.f;
}

__global__ __launch_bounds__(256, 4) void vq_main(
    const float* __restrict__ z, const unsigned short* __restrict__ bsplit,
    const float* __restrict__ cbn, const float* __restrict__ cb,
    float* __restrict__ out_q, float* __restrict__ out_idx,
    unsigned int* __restrict__ hist, float* __restrict__ loss_acc) {
  // A' split-bf16 z tile: [32 rows][128 inner], stride 136.
  __shared__ unsigned short Ash[ROWS * 136];
  __shared__ float srzp[ROWS * 16];
  __shared__ float srz[ROWS];
  __shared__ float candd[4][ROWS][17];  // +1 pad
  __shared__ int candk[4][ROWS][17];
  __shared__ int skf[ROWS];
  __shared__ float swav[4];

  const int tid = threadIdx.x;
  const int lane = tid & 63;
  const int wav = tid >> 6;
  const int quad = lane >> 4;
  const int col = lane & 15;
  const int rowbase = blockIdx.x * ROWS;

  // ---- prologue: load z tile (coalesced), split to bf16 hi/lo, row norms
  const float4* z4 = (const float4*)(z + (size_t)rowbase * D);
#pragma unroll
  for (int it = 0; it < ROWS / 16; ++it) {
    int f4 = it * 256 + tid;  // row*16 + (c4/4)
    int row = f4 >> 4, c4 = (f4 & 15) * 4;
    float4 v = z4[f4];
    srzp[f4] = ((v.x * v.x + v.y * v.y) + (v.z * v.z + v.w * v.w));
    unsigned short h0 = f2bf(v.x), h1 = f2bf(v.y), h2 = f2bf(v.z), h3 = f2bf(v.w);
    short4v hv = {(short)h0, (short)h1, (short)h2, (short)h3};
    short4v lv = {(short)f2bf(v.x - bf2f(h0)), (short)f2bf(v.y - bf2f(h1)),
                  (short)f2bf(v.z - bf2f(h2)), (short)f2bf(v.w - bf2f(h3))};
    *(short4v*)&Ash[row * 136 + c4] = hv;
    *(short4v*)&Ash[row * 136 + 64 + c4] = lv;
  }
  __syncthreads();
  if (tid < ROWS) {
    float s = 0.f;
#pragma unroll
    for (int i = 0; i < 16; ++i) s += srzp[tid * 16 + i];
    srz[tid] = s;
  }
  __syncthreads();

  // rz per (m-tile, reg): lane holds C rows mt*16 + quad*4 + reg
  float rzv[MT * 4];
#pragma unroll
  for (int mt = 0; mt < MT; ++mt)
#pragma unroll
    for (int reg = 0; reg < 4; ++reg)
      rzv[mt * 4 + reg] = srz[mt * 16 + quad * 4 + reg];

  // A fragments in registers: a[mt][{hi0,hi1,lo0,lo1}], 8 bf16 each.
  // A-operand layout: lane holds A[m = col][k = quad*8 + j].
  short8 a[MT][4];
#pragma unroll
  for (int mt = 0; mt < MT; ++mt) {
    const unsigned short* base = &Ash[(mt * 16 + col) * 136 + quad * 8];
    a[mt][0] = *(const short8*)(base + 0);    // z_hi k 0..31
    a[mt][1] = *(const short8*)(base + 32);   // z_hi k 32..63
    a[mt][2] = *(const short8*)(base + 64);   // z_lo k 0..31
    a[mt][3] = *(const short8*)(base + 96);   // z_lo k 32..63
  }

  float bestd[MT * 4];
  int bestk[MT * 4];
#pragma unroll
  for (int i = 0; i < MT * 4; ++i) {
    bestd[i] = 3.4e38f;
    bestk[i] = 0;
  }

  // Each wave scans 256 codes in 16 k-tiles of 16 codes.
  const int k0 = wav * 256;
  for (int kt = 0; kt < 16; ++kt) {
    const int mycode = k0 + kt * 16 + col;
    // B-operand layout: lane holds B[n = col (code)][k = quad*8 + j].
    const unsigned short* bb = bsplit + (size_t)mycode * 128 + quad * 8;
    short8 b0 = *(const short8*)(bb + 0);    // e_hi k 0..31
    short8 b1 = *(const short8*)(bb + 32);   // e_hi k 32..63
    short8 b2 = *(const short8*)(bb + 64);   // e_lo k 0..31
    short8 b3 = *(const short8*)(bb + 96);   // e_lo k 32..63
    const float en = cbn[mycode];

    f32x4 acc[MT];
#pragma unroll
    for (int mt = 0; mt < MT; ++mt) acc[mt] = {0.f, 0.f, 0.f, 0.f};
    // 6 products per mt, MT independent chains
#pragma unroll
    for (int mt = 0; mt < MT; ++mt)
      acc[mt] = __builtin_amdgcn_mfma_f32_16x16x32_bf16(a[mt][0], b0, acc[mt], 0, 0, 0);
#pragma unroll
    for (int mt = 0; mt < MT; ++mt)
      acc[mt] = __builtin_amdgcn_mfma_f32_16x16x32_bf16(a[mt][1], b1, acc[mt], 0, 0, 0);
#pragma unroll
    for (int mt = 0; mt < MT; ++mt)
      acc[mt] = __builtin_amdgcn_mfma_f32_16x16x32_bf16(a[mt][2], b0, acc[mt], 0, 0, 0);
#pragma unroll
    for (int mt = 0; mt < MT; ++mt)
      acc[mt] = __builtin_amdgcn_mfma_f32_16x16x32_bf16(a[mt][3], b1, acc[mt], 0, 0, 0);
#pragma unroll
    for (int mt = 0; mt < MT; ++mt)
      acc[mt] = __builtin_amdgcn_mfma_f32_16x16x32_bf16(a[mt][0], b2, acc[mt], 0, 0, 0);
#pragma unroll
    for (int mt = 0; mt < MT; ++mt)
      acc[mt] = __builtin_amdgcn_mfma_f32_16x16x32_bf16(a[mt][1], b3, acc[mt], 0, 0, 0);

    // fold into running argmin; C/D layout: col=lane&15, row=quad*4+reg
#pragma unroll
    for (int mt = 0; mt < MT; ++mt)
#pragma unroll
      for (int reg = 0; reg < 4; ++reg) {
        float dist = fmaf(-2.0f, acc[mt][reg], rzv[mt * 4 + reg] + en);
        int i = mt * 4 + reg;
        bool better = dist < bestd[i];  // strict <: ascending k keeps lowest
        bestk[i] = better ? mycode : bestk[i];
        bestd[i] = better ? dist : bestd[i];
      }
  }

  // publish per-lane candidates: per row, 16 col-classes x 4 waves
#pragma unroll
  for (int mt = 0; mt < MT; ++mt)
#pragma unroll
    for (int reg = 0; reg < 4; ++reg) {
      int row = mt * 16 + quad * 4 + reg;
      candd[wav][row][col] = bestd[mt * 4 + reg];
      candk[wav][row][col] = bestk[mt * 4 + reg];
    }
  __syncthreads();

  // ---- final per-row argmin with top-2 + exact fp32 recheck (R3 arithmetic)
  if (tid < ROWS) {
    float bd1 = 3.4e38f, bd2 = 3.4e38f;
    int bk1 = 0x7fffffff, bk2 = 0x7fffffff;
#pragma unroll
    for (int w = 0; w < 4; ++w)
      for (int c = 0; c < 16; ++c) {
        float dv = candd[w][tid][c];
        int kv = candk[w][tid][c];
        bool b1 = (dv < bd1) || (dv == bd1 && kv < bk1);
        bool b2 = (dv < bd2) || (dv == bd2 && kv < bk2);
        if (b1) {
          bd2 = bd1; bk2 = bk1;
          bd1 = dv; bk1 = kv;
        } else if (b2) {
          bd2 = dv; bk2 = kv;
        }
      }
    if (bd2 - bd1 < 1e-3f) {
      // exact fp32 recompute, bit-identical to the R3 kernel's arithmetic
      const int grow = rowbase + tid;
      const float4* zp = (const float4*)(z + (size_t)grow * D);
      float s0 = 0.f, s1 = 0.f, s2 = 0.f, s3 = 0.f;
#pragma unroll
      for (int i = 0; i < 16; ++i) {
        float4 v = zp[i];
        s0 = fmaf(v.x, v.x, s0);
        s1 = fmaf(v.y, v.y, s1);
        s2 = fmaf(v.z, v.z, s2);
        s3 = fmaf(v.w, v.w, s3);
      }
      const float rzx = (s0 + s1) + (s2 + s3);
      float dx[2];
      int kk[2] = {bk1, bk2};
#pragma unroll
      for (int c = 0; c < 2; ++c) {
        const float4* e4 = (const float4*)(cb + (size_t)kk[c] * D);
        float d0 = 0.f, d1 = 0.f, d2 = 0.f, d3 = 0.f;
#pragma unroll
        for (int i = 0; i < 16; ++i) {
          float4 v = e4[i];
          float4 zv = zp[i];
          d0 = fmaf(zv.x, v.x, d0);
          d1 = fmaf(zv.y, v.y, d1);
          d2 = fmaf(zv.z, v.z, d2);
          d3 = fmaf(zv.w, v.w, d3);
        }
        float dot = (d0 + d1) + (d2 + d3);
        dx[c] = (rzx + cbn[kk[c]]) - 2.0f * dot;
      }
      if ((dx[1] < dx[0]) || (dx[1] == dx[0] && bk2 < bk1)) bk1 = bk2;
    }
    skf[tid] = bk1;
    out_idx[rowbase + tid] = (float)bk1;
    atomicAdd(&hist[bk1], 1u);
  }
  __syncthreads();

  // ---- epilogue: quantized write (exact fp32 codebook rows) + loss partial
  float lsum = 0.f;
#pragma unroll
  for (int it = 0; it < ROWS / 16; ++it) {
    int f4 = it * 256 + tid;
    int r = f4 >> 4;
    int c4 = (f4 & 15) * 4;
    int bk = skf[r];
    const float4 q = *(const float4*)(cb + (size_t)bk * D + c4);
    const int grow = rowbase + r;
    const float4 zv = *(const float4*)(z + (size_t)grow * D + c4);
    *(float4*)(out_q + (size_t)grow * D + c4) = q;
    float ax = q.x - zv.x, ay = q.y - zv.y, az = q.z - zv.z, aw = q.w - zv.w;
    lsum += ax * ax + ay * ay + az * az + aw * aw;
  }
#pragma unroll
  for (int off = 32; off > 0; off >>= 1) lsum += __shfl_down(lsum, off, 64);
  if (lane == 0) swav[wav] = lsum;
  __syncthreads();
  if (tid == 0) {
    atomicAdd(loss_acc, (swav[0] + swav[1]) + (swav[2] + swav[3]));
  }
}

__global__ __launch_bounds__(1024) void vq_final(
    const unsigned int* __restrict__ hist, const float* __restrict__ loss_acc,
    float* __restrict__ out_loss, float* __restrict__ out_perp, float inv_n,
    float inv_nd) {
  __shared__ float part[16];
  const int t = threadIdx.x;
  const int lane = t & 63;
  const int wav = t >> 6;
  float p = (float)hist[t] * inv_n;
  float v = p * logf(p + 1e-10f);
#pragma unroll
  for (int off = 32; off > 0; off >>= 1) v += __shfl_down(v, off, 64);
  if (lane == 0) part[wav] = v;
  __syncthreads();
  if (t == 0) {
    float s = 0.f;
#pragma unroll
    for (int j = 0; j < 16; ++j) s += part[j];
    *out_perp = expf(-s);
    // q_latent + 0.25*e_latent, both numerically mean((q-z)^2)
    *out_loss = 1.25f * loss_acc[0] * inv_nd;
  }
}

extern "C" void kernel_launch(void* const* d_in, const int* in_sizes, int n_in,
                              void* d_out, int out_size, void* d_ws,
                              size_t ws_size, hipStream_t stream) {
  (void)n_in;
  (void)out_size;
  (void)ws_size;
  const float* z = (const float*)d_in[0];
  const float* cb = (const float*)d_in[1];
  const int N = in_sizes[0] / D;  // 32768

  // Output layout (flat float32, reference return order):
  float* out_q = (float*)d_out;                     // N*D
  float* out_loss = (float*)d_out + (size_t)N * D;  // 1
  float* out_idx = out_loss + 1;                    // N
  float* out_perp = out_idx + N;                    // 1

  // Workspace (floats): hist[1024] @0, loss_acc @1024, cbn[1024] @1040,
  // bsplit (short[1024*128]) @ float-idx 2064 (byte 8256, 16B-aligned).
  unsigned int* hist = (unsigned int*)d_ws;
  float* loss_acc = (float*)d_ws + 1024;
  float* cbn = (float*)d_ws + 1040;
  unsigned short* bsplit = (unsigned short*)((float*)d_ws + 2064);

  vq_prep<<<dim3(KC / 256), dim3(256), 0, stream>>>(cb, bsplit, cbn, hist,
                                                    loss_acc);
  vq_main<<<dim3(N / ROWS), dim3(256), 0, stream>>>(z, bsplit, cbn, cb, out_q,
                                                    out_idx, hist, loss_acc);
  vq_final<<<dim3(1), dim3(1024), 0, stream>>>(
      hist, loss_acc, out_loss, out_perp, 1.0f / (float)N,
      1.0f / ((float)N * (float)D));
}

// Round 6
// 105.476 us; speedup vs baseline: 1.2515x; 1.2515x over previous
//
#include <hip/hip_runtime.h>
#include <math.h>

// VQ-VAE vector quantizer for MI355X (gfx950).
// z: [32768, 64] fp32, codebook: [1024, 64] fp32.
// Outputs (flat float32, concatenated): quantized_st [32768*64], vq_loss [1],
// indices [32768] (as float), perplexity [1].
//
// R6: R5 (32 rows/block + launch_bounds(256,4)) FAILED: compiler chased 8
// waves/SIMD and allocated only 64 VGPRs -> A-frags rematerialized from LDS
// every kt (MfmaUtil 6.5%). Revert to R4's structure (mt=4, 64 rows/block,
// (256,2) -> 124 VGPRs, the known-good allocation) and fix R4's real stall
// (exposed per-kt B-load latency, MfmaUtil 11.6%) with register prefetch of
// the next kt's B-fragments + norm: loads overlap the 24-MFMA issue block.
// Numerics unchanged (3-term split-bf16 + exact fp32 recheck, margin 1e-3).

#define D 64
#define KC 1024
#define MT 4              // 16-row m-tiles per wave
#define ROWS (MT * 16)    // 64 rows per block

typedef short short8 __attribute__((ext_vector_type(8)));
typedef short short4v __attribute__((ext_vector_type(4)));
typedef float f32x4 __attribute__((ext_vector_type(4)));

__device__ __forceinline__ unsigned short f2bf(float x) {
  unsigned int u = __float_as_uint(x);
  unsigned int r = (u + 0x7fffu + ((u >> 16) & 1u)) >> 16;
  return (unsigned short)r;
}
__device__ __forceinline__ float bf2f(unsigned short h) {
  return __uint_as_float((unsigned int)h << 16);
}

// Precompute: exact fp32 code norms, split-bf16 codebook
// bsplit[k][128] = [e_hi(64) | e_lo(64)], zero hist/loss.
__global__ __launch_bounds__(256) void vq_prep(
    const float* __restrict__ cb, unsigned short* __restrict__ bsplit,
    float* __restrict__ cbn, unsigned int* __restrict__ hist,
    float* __restrict__ loss_acc) {
  const int k = blockIdx.x * 256 + threadIdx.x;  // 0..1023
  const float4* e = (const float4*)(cb + (size_t)k * D);
  unsigned short* bp = bsplit + (size_t)k * 128;
  float s0 = 0.f, s1 = 0.f, s2 = 0.f, s3 = 0.f;
#pragma unroll
  for (int i = 0; i < 16; ++i) {
    float4 v = e[i];
    s0 = fmaf(v.x, v.x, s0);
    s1 = fmaf(v.y, v.y, s1);
    s2 = fmaf(v.z, v.z, s2);
    s3 = fmaf(v.w, v.w, s3);
    unsigned short h0 = f2bf(v.x), h1 = f2bf(v.y), h2 = f2bf(v.z), h3 = f2bf(v.w);
    short4v hv = {(short)h0, (short)h1, (short)h2, (short)h3};
    short4v lv = {(short)f2bf(v.x - bf2f(h0)), (short)f2bf(v.y - bf2f(h1)),
                  (short)f2bf(v.z - bf2f(h2)), (short)f2bf(v.w - bf2f(h3))};
    *(short4v*)(bp + i * 4) = hv;
    *(short4v*)(bp + 64 + i * 4) = lv;
  }
  cbn[k] = (s0 + s1) + (s2 + s3);
  hist[k] = 0u;
  if (k == 0) loss_acc[0] = 0.f;
}

__global__ __launch_bounds__(256, 2) void vq_main(
    const float* __restrict__ z, const unsigned short* __restrict__ bsplit,
    const float* __restrict__ cbn, const float* __restrict__ cb,
    float* __restrict__ out_q, float* __restrict__ out_idx,
    unsigned int* __restrict__ hist, float* __restrict__ loss_acc) {
  // A' split-bf16 z tile: [64 rows][128 inner], stride 136 (bank-skew).
  __shared__ unsigned short Ash[ROWS * 136];
  __shared__ float srzp[ROWS * 16];
  __shared__ float srz[ROWS];
  __shared__ float candd[4][ROWS][17];  // +1 pad
  __shared__ int candk[4][ROWS][17];
  __shared__ int skf[ROWS];
  __shared__ float swav[4];

  const int tid = threadIdx.x;
  const int lane = tid & 63;
  const int wav = tid >> 6;
  const int quad = lane >> 4;
  const int col = lane & 15;
  const int rowbase = blockIdx.x * ROWS;

  // ---- prologue: load z tile (coalesced), split to bf16 hi/lo, row norms
  const float4* z4 = (const float4*)(z + (size_t)rowbase * D);
#pragma unroll
  for (int it = 0; it < ROWS / 16; ++it) {
    int f4 = it * 256 + tid;  // row*16 + (c4/4)
    int row = f4 >> 4, c4 = (f4 & 15) * 4;
    float4 v = z4[f4];
    srzp[f4] = ((v.x * v.x + v.y * v.y) + (v.z * v.z + v.w * v.w));
    unsigned short h0 = f2bf(v.x), h1 = f2bf(v.y), h2 = f2bf(v.z), h3 = f2bf(v.w);
    short4v hv = {(short)h0, (short)h1, (short)h2, (short)h3};
    short4v lv = {(short)f2bf(v.x - bf2f(h0)), (short)f2bf(v.y - bf2f(h1)),
                  (short)f2bf(v.z - bf2f(h2)), (short)f2bf(v.w - bf2f(h3))};
    *(short4v*)&Ash[row * 136 + c4] = hv;
    *(short4v*)&Ash[row * 136 + 64 + c4] = lv;
  }
  __syncthreads();
  if (tid < ROWS) {
    float s = 0.f;
#pragma unroll
    for (int i = 0; i < 16; ++i) s += srzp[tid * 16 + i];
    srz[tid] = s;
  }
  __syncthreads();

  // rz per (m-tile, reg): lane holds C rows mt*16 + quad*4 + reg
  float rzv[MT * 4];
#pragma unroll
  for (int mt = 0; mt < MT; ++mt)
#pragma unroll
    for (int reg = 0; reg < 4; ++reg)
      rzv[mt * 4 + reg] = srz[mt * 16 + quad * 4 + reg];

  // A fragments in registers: a[mt][{hi0,hi1,lo0,lo1}], 8 bf16 each.
  // A-operand layout: lane holds A[m = col][k = quad*8 + j].
  short8 a[MT][4];
#pragma unroll
  for (int mt = 0; mt < MT; ++mt) {
    const unsigned short* base = &Ash[(mt * 16 + col) * 136 + quad * 8];
    a[mt][0] = *(const short8*)(base + 0);    // z_hi k 0..31
    a[mt][1] = *(const short8*)(base + 32);   // z_hi k 32..63
    a[mt][2] = *(const short8*)(base + 64);   // z_lo k 0..31
    a[mt][3] = *(const short8*)(base + 96);   // z_lo k 32..63
  }

  float bestd[MT * 4];
  int bestk[MT * 4];
#pragma unroll
  for (int i = 0; i < MT * 4; ++i) {
    bestd[i] = 3.4e38f;
    bestk[i] = 0;
  }

  // Each wave scans 256 codes in 16 k-tiles of 16 codes, with the next
  // tile's B-fragments prefetched into registers (hides L2 latency under
  // the current tile's MFMA block).
  const int k0 = wav * 256;
  short8 nb0, nb1, nb2, nb3;
  float nen;
  {
    const unsigned short* bb = bsplit + (size_t)(k0 + col) * 128 + quad * 8;
    nb0 = *(const short8*)(bb + 0);
    nb1 = *(const short8*)(bb + 32);
    nb2 = *(const short8*)(bb + 64);
    nb3 = *(const short8*)(bb + 96);
    nen = cbn[k0 + col];
  }
  for (int kt = 0; kt < 16; ++kt) {
    const int mycode = k0 + kt * 16 + col;
    const short8 b0 = nb0, b1 = nb1, b2 = nb2, b3 = nb3;
    const float en = nen;
    if (kt < 15) {
      const unsigned short* nbb =
          bsplit + (size_t)(mycode + 16) * 128 + quad * 8;
      nb0 = *(const short8*)(nbb + 0);
      nb1 = *(const short8*)(nbb + 32);
      nb2 = *(const short8*)(nbb + 64);
      nb3 = *(const short8*)(nbb + 96);
      nen = cbn[mycode + 16];
    }

    f32x4 acc[MT];
#pragma unroll
    for (int mt = 0; mt < MT; ++mt) acc[mt] = {0.f, 0.f, 0.f, 0.f};
    // 6 products per mt, MT independent chains
#pragma unroll
    for (int mt = 0; mt < MT; ++mt)
      acc[mt] = __builtin_amdgcn_mfma_f32_16x16x32_bf16(a[mt][0], b0, acc[mt], 0, 0, 0);
#pragma unroll
    for (int mt = 0; mt < MT; ++mt)
      acc[mt] = __builtin_amdgcn_mfma_f32_16x16x32_bf16(a[mt][1], b1, acc[mt], 0, 0, 0);
#pragma unroll
    for (int mt = 0; mt < MT; ++mt)
      acc[mt] = __builtin_amdgcn_mfma_f32_16x16x32_bf16(a[mt][2], b0, acc[mt], 0, 0, 0);
#pragma unroll
    for (int mt = 0; mt < MT; ++mt)
      acc[mt] = __builtin_amdgcn_mfma_f32_16x16x32_bf16(a[mt][3], b1, acc[mt], 0, 0, 0);
#pragma unroll
    for (int mt = 0; mt < MT; ++mt)
      acc[mt] = __builtin_amdgcn_mfma_f32_16x16x32_bf16(a[mt][0], b2, acc[mt], 0, 0, 0);
#pragma unroll
    for (int mt = 0; mt < MT; ++mt)
      acc[mt] = __builtin_amdgcn_mfma_f32_16x16x32_bf16(a[mt][1], b3, acc[mt], 0, 0, 0);

    // fold into running argmin; C/D layout: col=lane&15, row=quad*4+reg
#pragma unroll
    for (int mt = 0; mt < MT; ++mt)
#pragma unroll
      for (int reg = 0; reg < 4; ++reg) {
        float dist = fmaf(-2.0f, acc[mt][reg], rzv[mt * 4 + reg] + en);
        int i = mt * 4 + reg;
        bool better = dist < bestd[i];  // strict <: ascending k keeps lowest
        bestk[i] = better ? mycode : bestk[i];
        bestd[i] = better ? dist : bestd[i];
      }
  }

  // publish per-lane candidates: per row, 16 col-classes x 4 waves
#pragma unroll
  for (int mt = 0; mt < MT; ++mt)
#pragma unroll
    for (int reg = 0; reg < 4; ++reg) {
      int row = mt * 16 + quad * 4 + reg;
      candd[wav][row][col] = bestd[mt * 4 + reg];
      candk[wav][row][col] = bestk[mt * 4 + reg];
    }
  __syncthreads();

  // ---- final per-row argmin with top-2 + exact fp32 recheck (R3 arithmetic)
  if (tid < ROWS) {
    float bd1 = 3.4e38f, bd2 = 3.4e38f;
    int bk1 = 0x7fffffff, bk2 = 0x7fffffff;
#pragma unroll
    for (int w = 0; w < 4; ++w)
      for (int c = 0; c < 16; ++c) {
        float dv = candd[w][tid][c];
        int kv = candk[w][tid][c];
        bool b1 = (dv < bd1) || (dv == bd1 && kv < bk1);
        bool b2 = (dv < bd2) || (dv == bd2 && kv < bk2);
        if (b1) {
          bd2 = bd1; bk2 = bk1;
          bd1 = dv; bk1 = kv;
        } else if (b2) {
          bd2 = dv; bk2 = kv;
        }
      }
    if (bd2 - bd1 < 1e-3f) {
      // exact fp32 recompute, bit-identical to the R3 kernel's arithmetic
      const int grow = rowbase + tid;
      const float4* zp = (const float4*)(z + (size_t)grow * D);
      float s0 = 0.f, s1 = 0.f, s2 = 0.f, s3 = 0.f;
#pragma unroll
      for (int i = 0; i < 16; ++i) {
        float4 v = zp[i];
        s0 = fmaf(v.x, v.x, s0);
        s1 = fmaf(v.y, v.y, s1);
        s2 = fmaf(v.z, v.z, s2);
        s3 = fmaf(v.w, v.w, s3);
      }
      const float rzx = (s0 + s1) + (s2 + s3);
      float dx[2];
      int kk[2] = {bk1, bk2};
#pragma unroll
      for (int c = 0; c < 2; ++c) {
        const float4* e4 = (const float4*)(cb + (size_t)kk[c] * D);
        float d0 = 0.f, d1 = 0.f, d2 = 0.f, d3 = 0.f;
#pragma unroll
        for (int i = 0; i < 16; ++i) {
          float4 v = e4[i];
          float4 zv = zp[i];
          d0 = fmaf(zv.x, v.x, d0);
          d1 = fmaf(zv.y, v.y, d1);
          d2 = fmaf(zv.z, v.z, d2);
          d3 = fmaf(zv.w, v.w, d3);
        }
        float dot = (d0 + d1) + (d2 + d3);
        dx[c] = (rzx + cbn[kk[c]]) - 2.0f * dot;
      }
      if ((dx[1] < dx[0]) || (dx[1] == dx[0] && bk2 < bk1)) bk1 = bk2;
    }
    skf[tid] = bk1;
    out_idx[rowbase + tid] = (float)bk1;
    atomicAdd(&hist[bk1], 1u);
  }
  __syncthreads();

  // ---- epilogue: quantized write (exact fp32 codebook rows) + loss partial
  float lsum = 0.f;
#pragma unroll
  for (int it = 0; it < ROWS / 16; ++it) {
    int f4 = it * 256 + tid;
    int r = f4 >> 4;
    int c4 = (f4 & 15) * 4;
    int bk = skf[r];
    const float4 q = *(const float4*)(cb + (size_t)bk * D + c4);
    const int grow = rowbase + r;
    const float4 zv = *(const float4*)(z + (size_t)grow * D + c4);
    *(float4*)(out_q + (size_t)grow * D + c4) = q;
    float ax = q.x - zv.x, ay = q.y - zv.y, az = q.z - zv.z, aw = q.w - zv.w;
    lsum += ax * ax + ay * ay + az * az + aw * aw;
  }
#pragma unroll
  for (int off = 32; off > 0; off >>= 1) lsum += __shfl_down(lsum, off, 64);
  if (lane == 0) swav[wav] = lsum;
  __syncthreads();
  if (tid == 0) {
    atomicAdd(loss_acc, (swav[0] + swav[1]) + (swav[2] + swav[3]));
  }
}

__global__ __launch_bounds__(1024) void vq_final(
    const unsigned int* __restrict__ hist, const float* __restrict__ loss_acc,
    float* __restrict__ out_loss, float* __restrict__ out_perp, float inv_n,
    float inv_nd) {
  __shared__ float part[16];
  const int t = threadIdx.x;
  const int lane = t & 63;
  const int wav = t >> 6;
  float p = (float)hist[t] * inv_n;
  float v = p * logf(p + 1e-10f);
#pragma unroll
  for (int off = 32; off > 0; off >>= 1) v += __shfl_down(v, off, 64);
  if (lane == 0) part[wav] = v;
  __syncthreads();
  if (t == 0) {
    float s = 0.f;
#pragma unroll
    for (int j = 0; j < 16; ++j) s += part[j];
    *out_perp = expf(-s);
    // q_latent + 0.25*e_latent, both numerically mean((q-z)^2)
    *out_loss = 1.25f * loss_acc[0] * inv_nd;
  }
}

extern "C" void kernel_launch(void* const* d_in, const int* in_sizes, int n_in,
                              void* d_out, int out_size, void* d_ws,
                              size_t ws_size, hipStream_t stream) {
  (void)n_in;
  (void)out_size;
  (void)ws_size;
  const float* z = (const float*)d_in[0];
  const float* cb = (const float*)d_in[1];
  const int N = in_sizes[0] / D;  // 32768

  // Output layout (flat float32, reference return order):
  float* out_q = (float*)d_out;                     // N*D
  float* out_loss = (float*)d_out + (size_t)N * D;  // 1
  float* out_idx = out_loss + 1;                    // N
  float* out_perp = out_idx + N;                    // 1

  // Workspace (floats): hist[1024] @0, loss_acc @1024, cbn[1024] @1040,
  // bsplit (short[1024*128]) @ float-idx 2064 (byte 8256, 16B-aligned).
  unsigned int* hist = (unsigned int*)d_ws;
  float* loss_acc = (float*)d_ws + 1024;
  float* cbn = (float*)d_ws + 1040;
  unsigned short* bsplit = (unsigned short*)((float*)d_ws + 2064);

  vq_prep<<<dim3(KC / 256), dim3(256), 0, stream>>>(cb, bsplit, cbn, hist,
                                                    loss_acc);
  vq_main<<<dim3(N / ROWS), dim3(256), 0, stream>>>(z, bsplit, cbn, cb, out_q,
                                                    out_idx, hist, loss_acc);
  vq_final<<<dim3(1), dim3(1024), 0, stream>>>(
      hist, loss_acc, out_loss, out_perp, 1.0f / (float)N,
      1.0f / ((float)N * (float)D));
}